// Round 2
// baseline (9962.538 us; speedup 1.0000x reference)
//
#include <hip/hip_runtime.h>
#include <math.h>

#define DSZ 128
#define VOX (DSZ*DSZ*DSZ)  // 2,097,152 voxels

// ---------------------------------------------------------------------------
// Dense 3x3x3 SAME conv, CIN -> COUT, optional bias / relu / L1-normalize.
// One thread per voxel, computes all COUT channels. Weights (OIDHW) staged in
// LDS (uniform broadcast reads). Coalesced along W (idx fastest dim = W).
// WT = output storage type (float or _Float16 for the normalized weight tensor).
// ---------------------------------------------------------------------------
template<int CIN, int COUT, bool RELU, bool NORM, bool BIAS, typename WT>
__global__ __launch_bounds__(256) void conv3x3(const float* __restrict__ in,
                                               const float* __restrict__ wgt,
                                               const float* __restrict__ bias,
                                               WT* __restrict__ out)
{
    __shared__ float lw[COUT * CIN * 27];
    __shared__ float lb[COUT];
    const int tid = threadIdx.x;
    for (int i = tid; i < COUT * CIN * 27; i += 256) lw[i] = wgt[i];
    if (BIAS) { if (tid < COUT) lb[tid] = bias[tid]; }
    __syncthreads();

    const int idx = blockIdx.x * 256 + tid;
    const int w = idx & (DSZ - 1);
    const int h = (idx >> 7) & (DSZ - 1);
    const int d = idx >> 14;

    float acc[COUT];
    #pragma unroll
    for (int oc = 0; oc < COUT; oc++) acc[oc] = BIAS ? lb[oc] : 0.0f;

    #pragma unroll 1
    for (int kd = 0; kd < 3; kd++) {
        const int z = d + kd - 1;
        const bool okz = ((unsigned)z < DSZ);
        #pragma unroll
        for (int kh = 0; kh < 3; kh++) {
            const int y = h + kh - 1;
            const bool oky = okz && ((unsigned)y < DSZ);
            #pragma unroll
            for (int kw = 0; kw < 3; kw++) {
                const int xx = w + kw - 1;
                const bool ok = oky && ((unsigned)xx < DSZ);
                const int off = ok ? ((z * DSZ + y) * DSZ + xx) : idx; // safe addr
                const int tap = kd * 9 + kh * 3 + kw;
                float v[CIN];
                #pragma unroll
                for (int ic = 0; ic < CIN; ic++) {
                    float t = in[(size_t)ic * VOX + off];
                    v[ic] = ok ? t : 0.0f;
                }
                #pragma unroll
                for (int oc = 0; oc < COUT; oc++) {
                    #pragma unroll
                    for (int ic = 0; ic < CIN; ic++)
                        acc[oc] = fmaf(v[ic], lw[(oc * CIN + ic) * 27 + tap], acc[oc]);
                }
            }
        }
    }

    if (RELU) {
        #pragma unroll
        for (int oc = 0; oc < COUT; oc++) acc[oc] = fmaxf(acc[oc], 0.0f);
    }
    if (NORM) {
        float s = 0.0f;
        #pragma unroll
        for (int oc = 0; oc < COUT; oc++) s += fabsf(acc[oc]);
        s = fmaxf(s, 1e-12f);
        const float r = 1.0f / s;
        #pragma unroll
        for (int oc = 0; oc < COUT; oc++) acc[oc] *= r;
    }
    #pragma unroll
    for (int oc = 0; oc < COUT; oc++) out[(size_t)oc * VOX + idx] = (WT)acc[oc];
}

// ---------------------------------------------------------------------------
// Adaptive (spatially-varying, channel-shared) 3x3x3 stencil:
//   out(c, p) = sum_t  in(c, p + offset_t - 1) * wb(t, p)     (zero padded)
// One thread per voxel; 27 per-voxel weights held in registers.
// ---------------------------------------------------------------------------
template<int C, bool TANH, typename WT>
__global__ __launch_bounds__(256) void aconv(const float* __restrict__ in,
                                             const WT* __restrict__ wb,
                                             float* __restrict__ out)
{
    const int idx = blockIdx.x * 256 + threadIdx.x;
    const int w = idx & (DSZ - 1);
    const int h = (idx >> 7) & (DSZ - 1);
    const int d = idx >> 14;

    float wv[27];
    #pragma unroll
    for (int t = 0; t < 27; t++) wv[t] = (float)wb[(size_t)t * VOX + idx];

    float acc[C];
    #pragma unroll
    for (int c = 0; c < C; c++) acc[c] = 0.0f;

    #pragma unroll 1
    for (int kd = 0; kd < 3; kd++) {
        const int z = d + kd - 1;
        const bool okz = ((unsigned)z < DSZ);
        #pragma unroll
        for (int kh = 0; kh < 3; kh++) {
            const int y = h + kh - 1;
            const bool oky = okz && ((unsigned)y < DSZ);
            #pragma unroll
            for (int kw = 0; kw < 3; kw++) {
                const int xx = w + kw - 1;
                const bool ok = oky && ((unsigned)xx < DSZ);
                const int off = ok ? ((z * DSZ + y) * DSZ + xx) : idx;
                const int tap = kd * 9 + kh * 3 + kw;
                #pragma unroll
                for (int c = 0; c < C; c++) {
                    float t = in[(size_t)c * VOX + off];
                    acc[c] = fmaf(ok ? t : 0.0f, wv[tap], acc[c]);
                }
            }
        }
    }

    #pragma unroll
    for (int c = 0; c < C; c++) {
        float r = TANH ? tanhf(acc[c]) : acc[c];
        out[(size_t)c * VOX + idx] = r;
    }
}

// ---------------------------------------------------------------------------
// Schedule (two 64MB regions R0/R1 + WB; F1/F2 live inside R0):
//  1. H1 = conv8x8relu(x)        -> R0
//  2. WB = conv8x27norm(R0)      -> WB      (H1 dead after this)
//  3.      aconv8(x,  WB)        -> R1
//  4.      aconv8(R1, WB)        -> R0
//  5.      aconv8(R0, WB)        -> R1      (block1 result)
//  6. M  = conv8x8(R1, mid)      -> R0      (R1 dead)
//  7. H2 = conv8x8relu(R0)       -> R1
//  8. WB = conv8x27norm(R1)      -> WB      (H2 dead)
//  9.      aconv8(R0, WB)        -> R1
// 10.      aconv8(R1, WB)        -> R0      (M dead after 9)
// 11.      aconv8(R0, WB)        -> R1      (mid2)
// 12. H3 = conv8x8relu(R1)       -> R0
// 13. WB = conv8x27norm(R0)      -> WB      (H3 dead)
// 14. F1 = conv8x1(R1, out_w)    -> R0[0:VOX)
// 15.      aconv1(F1, WB)        -> F2 = R0[VOX:2VOX)
// 16.      aconv1(F2, WB)        -> F1
// 17.      aconv1+tanh(F1, WB)   -> d_out
// ---------------------------------------------------------------------------
template<typename WT>
static void run_pipeline(const float* x, void* const* d_in, float* out,
                         float* R0, float* R1, WT* WB, hipStream_t stream)
{
    const float* ac1_w1 = (const float*)d_in[1];
    const float* ac1_b1 = (const float*)d_in[2];
    const float* ac1_w2 = (const float*)d_in[3];
    const float* ac2_w1 = (const float*)d_in[4];
    const float* ac2_b1 = (const float*)d_in[5];
    const float* ac2_w2 = (const float*)d_in[6];
    const float* ac3_w1 = (const float*)d_in[7];
    const float* ac3_b1 = (const float*)d_in[8];
    const float* ac3_w2 = (const float*)d_in[9];
    const float* mid_w  = (const float*)d_in[10];
    const float* mid_b  = (const float*)d_in[11];
    const float* out_w  = (const float*)d_in[12];
    const float* out_b  = (const float*)d_in[13];

    float* F1 = R0;
    float* F2 = R0 + VOX;

    const dim3 grid(VOX / 256), blk(256);

    // block 1
    conv3x3<8, 8,  true,  false, true,  float><<<grid, blk, 0, stream>>>(x,  ac1_w1, ac1_b1, R0);
    conv3x3<8, 27, false, true,  false, WT   ><<<grid, blk, 0, stream>>>(R0, ac1_w2, nullptr, WB);
    aconv<8, false, WT><<<grid, blk, 0, stream>>>(x,  WB, R1);
    aconv<8, false, WT><<<grid, blk, 0, stream>>>(R1, WB, R0);
    aconv<8, false, WT><<<grid, blk, 0, stream>>>(R0, WB, R1);
    // mid conv
    conv3x3<8, 8,  false, false, true,  float><<<grid, blk, 0, stream>>>(R1, mid_w, mid_b, R0);
    // block 2
    conv3x3<8, 8,  true,  false, true,  float><<<grid, blk, 0, stream>>>(R0, ac2_w1, ac2_b1, R1);
    conv3x3<8, 27, false, true,  false, WT   ><<<grid, blk, 0, stream>>>(R1, ac2_w2, nullptr, WB);
    aconv<8, false, WT><<<grid, blk, 0, stream>>>(R0, WB, R1);
    aconv<8, false, WT><<<grid, blk, 0, stream>>>(R1, WB, R0);
    aconv<8, false, WT><<<grid, blk, 0, stream>>>(R0, WB, R1);   // mid2
    // block 3 weights from mid2 (R1)
    conv3x3<8, 8,  true,  false, true,  float><<<grid, blk, 0, stream>>>(R1, ac3_w1, ac3_b1, R0);
    conv3x3<8, 27, false, true,  false, WT   ><<<grid, blk, 0, stream>>>(R0, ac3_w2, nullptr, WB);
    conv3x3<8, 1,  false, false, true,  float><<<grid, blk, 0, stream>>>(R1, out_w, out_b, F1);
    aconv<1, false, WT><<<grid, blk, 0, stream>>>(F1, WB, F2);
    aconv<1, false, WT><<<grid, blk, 0, stream>>>(F2, WB, F1);
    aconv<1, true,  WT><<<grid, blk, 0, stream>>>(F1, WB, out);
}

extern "C" void kernel_launch(void* const* d_in, const int* in_sizes, int n_in,
                              void* d_out, int out_size, void* d_ws, size_t ws_size,
                              hipStream_t stream)
{
    const float* x = (const float*)d_in[0];
    float* out = (float*)d_out;

    char* ws = (char*)d_ws;
    const size_t CH8 = (size_t)8 * VOX * sizeof(float);          // 64 MB region
    float* R0 = (float*)(ws);
    float* R1 = (float*)(ws + CH8);
    void*  WBp = (void*)(ws + 2 * CH8);

    const size_t need_f32 = 2 * CH8 + (size_t)27 * VOX * sizeof(float);   // 344 MB
    // fp16 plan needs 2*CH8 + 27*VOX*2 = 236 MB

    if (ws_size >= need_f32) {
        run_pipeline<float>(x, d_in, out, R0, R1, (float*)WBp, stream);
    } else {
        run_pipeline<_Float16>(x, d_in, out, R0, R1, (_Float16*)WBp, stream);
    }
}

// Round 3
// 4508.041 us; speedup vs baseline: 2.2099x; 2.2099x over previous
//
#include <hip/hip_runtime.h>
#include <math.h>

#define DSZ 128
#define VOX (DSZ*DSZ*DSZ)  // 2,097,152 voxels

// ---------------------------------------------------------------------------
// Dense 3x3x3 SAME conv, CIN -> COUT, optional bias / relu. One thread per
// voxel, all COUT channels. Weights staged in LDS (broadcast reads).
// ---------------------------------------------------------------------------
template<int CIN, int COUT, bool RELU, bool BIAS>
__global__ __launch_bounds__(256) void conv3x3(const float* __restrict__ in,
                                               const float* __restrict__ wgt,
                                               const float* __restrict__ bias,
                                               float* __restrict__ out)
{
    __shared__ float lw[COUT * CIN * 27];
    __shared__ float lb[COUT];
    const int tid = threadIdx.x;
    for (int i = tid; i < COUT * CIN * 27; i += 256) lw[i] = wgt[i];
    if (BIAS) { if (tid < COUT) lb[tid] = bias[tid]; }
    __syncthreads();

    const int idx = blockIdx.x * 256 + tid;
    const int w = idx & (DSZ - 1);
    const int h = (idx >> 7) & (DSZ - 1);
    const int d = idx >> 14;

    float acc[COUT];
    #pragma unroll
    for (int oc = 0; oc < COUT; oc++) acc[oc] = BIAS ? lb[oc] : 0.0f;

    #pragma unroll 1
    for (int kd = 0; kd < 3; kd++) {
        const int z = d + kd - 1;
        const bool okz = ((unsigned)z < DSZ);
        #pragma unroll
        for (int kh = 0; kh < 3; kh++) {
            const int y = h + kh - 1;
            const bool oky = okz && ((unsigned)y < DSZ);
            #pragma unroll
            for (int kw = 0; kw < 3; kw++) {
                const int xx = w + kw - 1;
                const bool ok = oky && ((unsigned)xx < DSZ);
                const int off = ok ? ((z * DSZ + y) * DSZ + xx) : idx;
                const int tap = kd * 9 + kh * 3 + kw;
                float v[CIN];
                #pragma unroll
                for (int ic = 0; ic < CIN; ic++) {
                    float t = in[(size_t)ic * VOX + off];
                    v[ic] = ok ? t : 0.0f;
                }
                #pragma unroll
                for (int oc = 0; oc < COUT; oc++) {
                    #pragma unroll
                    for (int ic = 0; ic < CIN; ic++)
                        acc[oc] = fmaf(v[ic], lw[(oc * CIN + ic) * 27 + tap], acc[oc]);
                }
            }
        }
    }

    if (RELU) {
        #pragma unroll
        for (int oc = 0; oc < COUT; oc++) acc[oc] = fmaxf(acc[oc], 0.0f);
    }
    #pragma unroll
    for (int oc = 0; oc < COUT; oc++) out[(size_t)oc * VOX + idx] = acc[oc];
}

// ---------------------------------------------------------------------------
// 8 -> 27 conv + L1 normalize, restructured for occupancy:
//   block = 256 threads = 4 waves, covers 128 voxels (lane, lane+64).
//   wave w computes output channels [7w, 7w+min(7,27-7w)).
//   weights in LDS as [tap][oc][ic] so each (tap,oc) row is 2 float4 reads.
//   L1 denom: per-wave partial |sum| -> LDS -> all-reduce across 4 waves.
// ---------------------------------------------------------------------------
template<typename WT>
__global__ __launch_bounds__(256, 4) void conv8x27n(const float* __restrict__ in,
                                                    const float* __restrict__ wgt,
                                                    WT* __restrict__ out)
{
    __shared__ float lw[27 * 216 + 8];   // [tap][oc][ic], +8 pad for wave3's 7th oc
    __shared__ float red[2][64][5];      // [vslot][lane][wave], padded stride 5
    const int tid = threadIdx.x;
    for (int i = tid; i < 27 * 216; i += 256) {
        const int oc = i / 216, ic = (i / 27) & 7, tap = i % 27;
        lw[tap * 216 + oc * 8 + ic] = wgt[i];
    }
    if (tid < 8) lw[27 * 216 + tid] = 0.0f;  // pad so wave3 j=6 reads zeros at tap==26
    __syncthreads();

    const int lane = tid & 63;
    const int wv   = tid >> 6;                 // 0..3
    const int noc  = (wv == 3) ? 6 : 7;
    const int oc0  = 7 * wv;

    const int idx0 = blockIdx.x * 128 + lane;  // w = lane
    const int idx1 = idx0 + 64;                // w = lane + 64
    const int h = blockIdx.x & 127;
    const int d = blockIdx.x >> 7;

    float acc[7][2];
    #pragma unroll
    for (int j = 0; j < 7; j++) { acc[j][0] = 0.0f; acc[j][1] = 0.0f; }

    #pragma unroll 1
    for (int kd = 0; kd < 3; kd++) {
        const int z = d + kd - 1;
        const bool okz = ((unsigned)z < DSZ);
        #pragma unroll
        for (int kh = 0; kh < 3; kh++) {
            const int y = h + kh - 1;
            const bool oky = okz && ((unsigned)y < DSZ);
            const int offzy = (z * DSZ + y) * DSZ;
            #pragma unroll
            for (int kw = 0; kw < 3; kw++) {
                const int x0 = lane + kw - 1;
                const int x1 = lane + 64 + kw - 1;
                const bool ok0 = oky && ((unsigned)x0 < DSZ);
                const bool ok1 = oky && ((unsigned)x1 < DSZ);
                const int o0 = ok0 ? offzy + x0 : idx0;
                const int o1 = ok1 ? offzy + x1 : idx1;
                const int tap = kd * 9 + kh * 3 + kw;

                float v0[8], v1[8];
                #pragma unroll
                for (int ic = 0; ic < 8; ic++) {
                    float t0 = in[(size_t)ic * VOX + o0];
                    float t1 = in[(size_t)ic * VOX + o1];
                    v0[ic] = ok0 ? t0 : 0.0f;
                    v1[ic] = ok1 ? t1 : 0.0f;
                }
                const float4* wp = (const float4*)&lw[tap * 216 + oc0 * 8];
                #pragma unroll
                for (int j = 0; j < 7; j++) {
                    const float4 wa = wp[2 * j];
                    const float4 wb = wp[2 * j + 1];
                    float a0 = acc[j][0], a1 = acc[j][1];
                    a0 = fmaf(wa.x, v0[0], a0); a1 = fmaf(wa.x, v1[0], a1);
                    a0 = fmaf(wa.y, v0[1], a0); a1 = fmaf(wa.y, v1[1], a1);
                    a0 = fmaf(wa.z, v0[2], a0); a1 = fmaf(wa.z, v1[2], a1);
                    a0 = fmaf(wa.w, v0[3], a0); a1 = fmaf(wa.w, v1[3], a1);
                    a0 = fmaf(wb.x, v0[4], a0); a1 = fmaf(wb.x, v1[4], a1);
                    a0 = fmaf(wb.y, v0[5], a0); a1 = fmaf(wb.y, v1[5], a1);
                    a0 = fmaf(wb.z, v0[6], a0); a1 = fmaf(wb.z, v1[6], a1);
                    a0 = fmaf(wb.w, v0[7], a0); a1 = fmaf(wb.w, v1[7], a1);
                    acc[j][0] = a0; acc[j][1] = a1;
                }
            }
        }
    }

    float s0 = 0.0f, s1 = 0.0f;
    for (int j = 0; j < noc; j++) { s0 += fabsf(acc[j][0]); s1 += fabsf(acc[j][1]); }
    red[0][lane][wv] = s0;
    red[1][lane][wv] = s1;
    __syncthreads();
    const float t0 = red[0][lane][0] + red[0][lane][1] + red[0][lane][2] + red[0][lane][3];
    const float t1 = red[1][lane][0] + red[1][lane][1] + red[1][lane][2] + red[1][lane][3];
    const float r0 = 1.0f / fmaxf(t0, 1e-12f);
    const float r1 = 1.0f / fmaxf(t1, 1e-12f);
    for (int j = 0; j < noc; j++) {
        out[(size_t)(oc0 + j) * VOX + idx0] = (WT)(acc[j][0] * r0);
        out[(size_t)(oc0 + j) * VOX + idx1] = (WT)(acc[j][1] * r1);
    }
}

// ---------------------------------------------------------------------------
// Adaptive stencil: out(c,p) = sum_t in(c, p+off_t) * wb(t,p), zero padded.
// ---------------------------------------------------------------------------
template<int C, bool TANH, typename WT>
__global__ __launch_bounds__(256) void aconv(const float* __restrict__ in,
                                             const WT* __restrict__ wb,
                                             float* __restrict__ out)
{
    const int idx = blockIdx.x * 256 + threadIdx.x;
    const int w = idx & (DSZ - 1);
    const int h = (idx >> 7) & (DSZ - 1);
    const int d = idx >> 14;

    float wv[27];
    #pragma unroll
    for (int t = 0; t < 27; t++) wv[t] = (float)wb[(size_t)t * VOX + idx];

    float acc[C];
    #pragma unroll
    for (int c = 0; c < C; c++) acc[c] = 0.0f;

    #pragma unroll 1
    for (int kd = 0; kd < 3; kd++) {
        const int z = d + kd - 1;
        const bool okz = ((unsigned)z < DSZ);
        #pragma unroll
        for (int kh = 0; kh < 3; kh++) {
            const int y = h + kh - 1;
            const bool oky = okz && ((unsigned)y < DSZ);
            #pragma unroll
            for (int kw = 0; kw < 3; kw++) {
                const int xx = w + kw - 1;
                const bool ok = oky && ((unsigned)xx < DSZ);
                const int off = ok ? ((z * DSZ + y) * DSZ + xx) : idx;
                const int tap = kd * 9 + kh * 3 + kw;
                #pragma unroll
                for (int c = 0; c < C; c++) {
                    float t = in[(size_t)c * VOX + off];
                    acc[c] = fmaf(ok ? t : 0.0f, wv[tap], acc[c]);
                }
            }
        }
    }

    #pragma unroll
    for (int c = 0; c < C; c++) {
        float r = TANH ? tanhf(acc[c]) : acc[c];
        out[(size_t)c * VOX + idx] = r;
    }
}

// ---------------------------------------------------------------------------
// Schedule: two 64MB regions R0/R1 + WB (fp32 or fp16 by ws_size ladder).
// ---------------------------------------------------------------------------
template<typename WT>
static void run_pipeline(const float* x, void* const* d_in, float* out,
                         float* R0, float* R1, WT* WB, hipStream_t stream)
{
    const float* ac1_w1 = (const float*)d_in[1];
    const float* ac1_b1 = (const float*)d_in[2];
    const float* ac1_w2 = (const float*)d_in[3];
    const float* ac2_w1 = (const float*)d_in[4];
    const float* ac2_b1 = (const float*)d_in[5];
    const float* ac2_w2 = (const float*)d_in[6];
    const float* ac3_w1 = (const float*)d_in[7];
    const float* ac3_b1 = (const float*)d_in[8];
    const float* ac3_w2 = (const float*)d_in[9];
    const float* mid_w  = (const float*)d_in[10];
    const float* mid_b  = (const float*)d_in[11];
    const float* out_w  = (const float*)d_in[12];
    const float* out_b  = (const float*)d_in[13];

    float* F1 = R0;
    float* F2 = R0 + VOX;

    const dim3 grid(VOX / 256), blk(256);
    const dim3 gridN(VOX / 128);   // conv8x27n: 128 voxels/block

    // block 1
    conv3x3<8, 8, true,  true><<<grid, blk, 0, stream>>>(x,  ac1_w1, ac1_b1, R0);
    conv8x27n<WT><<<gridN, blk, 0, stream>>>(R0, ac1_w2, WB);
    aconv<8, false, WT><<<grid, blk, 0, stream>>>(x,  WB, R1);
    aconv<8, false, WT><<<grid, blk, 0, stream>>>(R1, WB, R0);
    aconv<8, false, WT><<<grid, blk, 0, stream>>>(R0, WB, R1);
    // mid conv
    conv3x3<8, 8, false, true><<<grid, blk, 0, stream>>>(R1, mid_w, mid_b, R0);
    // block 2
    conv3x3<8, 8, true,  true><<<grid, blk, 0, stream>>>(R0, ac2_w1, ac2_b1, R1);
    conv8x27n<WT><<<gridN, blk, 0, stream>>>(R1, ac2_w2, WB);
    aconv<8, false, WT><<<grid, blk, 0, stream>>>(R0, WB, R1);
    aconv<8, false, WT><<<grid, blk, 0, stream>>>(R1, WB, R0);
    aconv<8, false, WT><<<grid, blk, 0, stream>>>(R0, WB, R1);   // mid2
    // block 3: weights from mid2 (R1)
    conv3x3<8, 8, true,  true><<<grid, blk, 0, stream>>>(R1, ac3_w1, ac3_b1, R0);
    conv8x27n<WT><<<gridN, blk, 0, stream>>>(R0, ac3_w2, WB);
    conv3x3<8, 1, false, true><<<grid, blk, 0, stream>>>(R1, out_w, out_b, F1);
    aconv<1, false, WT><<<grid, blk, 0, stream>>>(F1, WB, F2);
    aconv<1, false, WT><<<grid, blk, 0, stream>>>(F2, WB, F1);
    aconv<1, true,  WT><<<grid, blk, 0, stream>>>(F1, WB, out);
}

extern "C" void kernel_launch(void* const* d_in, const int* in_sizes, int n_in,
                              void* d_out, int out_size, void* d_ws, size_t ws_size,
                              hipStream_t stream)
{
    const float* x = (const float*)d_in[0];
    float* out = (float*)d_out;

    char* ws = (char*)d_ws;
    const size_t CH8 = (size_t)8 * VOX * sizeof(float);          // 64 MB region
    float* R0 = (float*)(ws);
    float* R1 = (float*)(ws + CH8);
    void*  WBp = (void*)(ws + 2 * CH8);

    const size_t need_f32 = 2 * CH8 + (size_t)27 * VOX * sizeof(float);   // 344 MB

    if (ws_size >= need_f32) {
        run_pipeline<float>(x, d_in, out, R0, R1, (float*)WBp, stream);
    } else {
        run_pipeline<_Float16>(x, d_in, out, R0, R1, (_Float16*)WBp, stream);
    }
}

// Round 4
// 3475.234 us; speedup vs baseline: 2.8667x; 1.2972x over previous
//
#include <hip/hip_runtime.h>
#include <math.h>

#define DSZ 128
#define VOX (DSZ*DSZ*DSZ)  // 2,097,152 voxels

// ---------------------------------------------------------------------------
// Dense 3x3x3 SAME conv, 8 -> COUT, bias, optional relu. LDS-tiled input:
// block = 256 threads = output tile 128(W) x 2(H) x 1(D), halo tile
// 8ch x 3(z) x 4(y) x 130(x) = 49,920 B LDS. Weights read straight from
// global with wave-uniform indices -> scalar (s_load) path, no VALU/LDS cost.
// ---------------------------------------------------------------------------
template<int COUT, bool RELU>
__global__ __launch_bounds__(256) void conv3x3t(const float* __restrict__ in,
                                                const float* __restrict__ wgt,
                                                const float* __restrict__ bias,
                                                float* __restrict__ out)
{
    __shared__ float tile[8 * 3 * 4 * 130];   // [ic][zz][yy][xx]
    const int tid = threadIdx.x;
    const int d0 = blockIdx.x >> 6;           // z plane
    const int h0 = (blockIdx.x & 63) << 1;    // first of 2 output rows

    const int x  = tid & 127;                 // w coordinate
    const int hi = tid >> 7;                  // 0/1: which output row

    // ---- stage input tile: 96 rows (ic,zz,yy) x 130, interior via 128 lanes
    #pragma unroll 4
    for (int it = 0; it < 48; ++it) {
        const int r  = it * 2 + hi;           // wave-uniform row id
        const int ic = r / 12;
        const int s  = r - ic * 12;
        const int zz = s >> 2;
        const int yy = s & 3;
        const int z = d0 + zz - 1;
        const int y = h0 + yy - 1;
        float v = 0.0f;
        if (((unsigned)z < DSZ) && ((unsigned)y < DSZ))
            v = in[(size_t)ic * VOX + (z << 14) + (y << 7) + x];
        tile[r * 130 + 1 + x] = v;
    }
    if (tid < 192) tile[(tid >> 1) * 130 + (tid & 1) * 129] = 0.0f; // x halo = global pad
    __syncthreads();

    float acc[COUT];
    #pragma unroll
    for (int oc = 0; oc < COUT; ++oc) acc[oc] = bias[oc];   // uniform -> scalar

    #pragma unroll
    for (int ic = 0; ic < 8; ++ic) {
        #pragma unroll
        for (int kd = 0; kd < 3; ++kd) {
            #pragma unroll
            for (int kh = 0; kh < 3; ++kh) {
                const float* tp = &tile[((ic * 3 + kd) * 4 + (hi + kh)) * 130 + x];
                const float t0 = tp[0], t1 = tp[1], t2 = tp[2];
                #pragma unroll
                for (int oc = 0; oc < COUT; ++oc) {
                    const float* wp = &wgt[(oc * 8 + ic) * 27 + kd * 9 + kh * 3];
                    acc[oc] = fmaf(t0, wp[0], acc[oc]);   // wp[*] uniform -> s_load
                    acc[oc] = fmaf(t1, wp[1], acc[oc]);
                    acc[oc] = fmaf(t2, wp[2], acc[oc]);
                }
            }
        }
    }

    const int idx = (d0 << 14) + ((h0 + hi) << 7) + x;
    #pragma unroll
    for (int oc = 0; oc < COUT; ++oc) {
        float r = acc[oc];
        if (RELU) r = fmaxf(r, 0.0f);
        out[(size_t)oc * VOX + idx] = r;
    }
}

// ---------------------------------------------------------------------------
// 8 -> 27 conv + L1 normalize (R2 design: 4 waves split 27 ocs, 2 voxels/thread)
// ---------------------------------------------------------------------------
template<typename WT>
__global__ __launch_bounds__(256, 4) void conv8x27n(const float* __restrict__ in,
                                                    const float* __restrict__ wgt,
                                                    WT* __restrict__ out)
{
    __shared__ float lw[27 * 216 + 8];   // [tap][oc][ic], +8 pad for wave3's 7th oc
    __shared__ float red[2][64][5];      // [vslot][lane][wave], padded stride 5
    const int tid = threadIdx.x;
    for (int i = tid; i < 27 * 216; i += 256) {
        const int oc = i / 216, ic = (i / 27) & 7, tap = i % 27;
        lw[tap * 216 + oc * 8 + ic] = wgt[i];
    }
    if (tid < 8) lw[27 * 216 + tid] = 0.0f;
    __syncthreads();

    const int lane = tid & 63;
    const int wv   = tid >> 6;
    const int noc  = (wv == 3) ? 6 : 7;
    const int oc0  = 7 * wv;

    const int idx0 = blockIdx.x * 128 + lane;
    const int idx1 = idx0 + 64;
    const int h = blockIdx.x & 127;
    const int d = blockIdx.x >> 7;

    float acc[7][2];
    #pragma unroll
    for (int j = 0; j < 7; j++) { acc[j][0] = 0.0f; acc[j][1] = 0.0f; }

    #pragma unroll 1
    for (int kd = 0; kd < 3; kd++) {
        const int z = d + kd - 1;
        const bool okz = ((unsigned)z < DSZ);
        #pragma unroll
        for (int kh = 0; kh < 3; kh++) {
            const int y = h + kh - 1;
            const bool oky = okz && ((unsigned)y < DSZ);
            const int offzy = (z * DSZ + y) * DSZ;
            #pragma unroll
            for (int kw = 0; kw < 3; kw++) {
                const int x0 = lane + kw - 1;
                const int x1 = lane + 64 + kw - 1;
                const bool ok0 = oky && ((unsigned)x0 < DSZ);
                const bool ok1 = oky && ((unsigned)x1 < DSZ);
                const int o0 = ok0 ? offzy + x0 : idx0;
                const int o1 = ok1 ? offzy + x1 : idx1;
                const int tap = kd * 9 + kh * 3 + kw;

                float v0[8], v1[8];
                #pragma unroll
                for (int ic = 0; ic < 8; ic++) {
                    float t0 = in[(size_t)ic * VOX + o0];
                    float t1 = in[(size_t)ic * VOX + o1];
                    v0[ic] = ok0 ? t0 : 0.0f;
                    v1[ic] = ok1 ? t1 : 0.0f;
                }
                const float4* wp = (const float4*)&lw[tap * 216 + oc0 * 8];
                #pragma unroll
                for (int j = 0; j < 7; j++) {
                    const float4 wa = wp[2 * j];
                    const float4 wb = wp[2 * j + 1];
                    float a0 = acc[j][0], a1 = acc[j][1];
                    a0 = fmaf(wa.x, v0[0], a0); a1 = fmaf(wa.x, v1[0], a1);
                    a0 = fmaf(wa.y, v0[1], a0); a1 = fmaf(wa.y, v1[1], a1);
                    a0 = fmaf(wa.z, v0[2], a0); a1 = fmaf(wa.z, v1[2], a1);
                    a0 = fmaf(wa.w, v0[3], a0); a1 = fmaf(wa.w, v1[3], a1);
                    a0 = fmaf(wb.x, v0[4], a0); a1 = fmaf(wb.x, v1[4], a1);
                    a0 = fmaf(wb.y, v0[5], a0); a1 = fmaf(wb.y, v1[5], a1);
                    a0 = fmaf(wb.z, v0[6], a0); a1 = fmaf(wb.z, v1[6], a1);
                    a0 = fmaf(wb.w, v0[7], a0); a1 = fmaf(wb.w, v1[7], a1);
                    acc[j][0] = a0; acc[j][1] = a1;
                }
            }
        }
    }

    float s0 = 0.0f, s1 = 0.0f;
    for (int j = 0; j < noc; j++) { s0 += fabsf(acc[j][0]); s1 += fabsf(acc[j][1]); }
    red[0][lane][wv] = s0;
    red[1][lane][wv] = s1;
    __syncthreads();
    const float t0 = red[0][lane][0] + red[0][lane][1] + red[0][lane][2] + red[0][lane][3];
    const float t1 = red[1][lane][0] + red[1][lane][1] + red[1][lane][2] + red[1][lane][3];
    const float r0 = 1.0f / fmaxf(t0, 1e-12f);
    const float r1 = 1.0f / fmaxf(t1, 1e-12f);
    for (int j = 0; j < noc; j++) {
        out[(size_t)(oc0 + j) * VOX + idx0] = (WT)(acc[j][0] * r0);
        out[(size_t)(oc0 + j) * VOX + idx1] = (WT)(acc[j][1] * r1);
    }
}

// ---------------------------------------------------------------------------
// Adaptive stencil: out(c,p) = sum_t in(c, p+off_t) * wb(t,p), zero padded.
// ---------------------------------------------------------------------------
template<int C, bool TANH, typename WT>
__global__ __launch_bounds__(256) void aconv(const float* __restrict__ in,
                                             const WT* __restrict__ wb,
                                             float* __restrict__ out)
{
    const int idx = blockIdx.x * 256 + threadIdx.x;
    const int w = idx & (DSZ - 1);
    const int h = (idx >> 7) & (DSZ - 1);
    const int d = idx >> 14;

    float wv[27];
    #pragma unroll
    for (int t = 0; t < 27; t++) wv[t] = (float)wb[(size_t)t * VOX + idx];

    float acc[C];
    #pragma unroll
    for (int c = 0; c < C; c++) acc[c] = 0.0f;

    #pragma unroll 1
    for (int kd = 0; kd < 3; kd++) {
        const int z = d + kd - 1;
        const bool okz = ((unsigned)z < DSZ);
        #pragma unroll
        for (int kh = 0; kh < 3; kh++) {
            const int y = h + kh - 1;
            const bool oky = okz && ((unsigned)y < DSZ);
            #pragma unroll
            for (int kw = 0; kw < 3; kw++) {
                const int xx = w + kw - 1;
                const bool ok = oky && ((unsigned)xx < DSZ);
                const int off = ok ? ((z * DSZ + y) * DSZ + xx) : idx;
                const int tap = kd * 9 + kh * 3 + kw;
                #pragma unroll
                for (int c = 0; c < C; c++) {
                    float t = in[(size_t)c * VOX + off];
                    acc[c] = fmaf(ok ? t : 0.0f, wv[tap], acc[c]);
                }
            }
        }
    }

    #pragma unroll
    for (int c = 0; c < C; c++) {
        float r = TANH ? tanhf(acc[c]) : acc[c];
        out[(size_t)c * VOX + idx] = r;
    }
}

// ---------------------------------------------------------------------------
template<typename WT>
static void run_pipeline(const float* x, void* const* d_in, float* out,
                         float* R0, float* R1, WT* WB, hipStream_t stream)
{
    const float* ac1_w1 = (const float*)d_in[1];
    const float* ac1_b1 = (const float*)d_in[2];
    const float* ac1_w2 = (const float*)d_in[3];
    const float* ac2_w1 = (const float*)d_in[4];
    const float* ac2_b1 = (const float*)d_in[5];
    const float* ac2_w2 = (const float*)d_in[6];
    const float* ac3_w1 = (const float*)d_in[7];
    const float* ac3_b1 = (const float*)d_in[8];
    const float* ac3_w2 = (const float*)d_in[9];
    const float* mid_w  = (const float*)d_in[10];
    const float* mid_b  = (const float*)d_in[11];
    const float* out_w  = (const float*)d_in[12];
    const float* out_b  = (const float*)d_in[13];

    float* F1 = R0;
    float* F2 = R0 + VOX;

    const dim3 grid(VOX / 256), blk(256);
    const dim3 gridN(VOX / 128);   // conv8x27n: 128 voxels/block
    const dim3 gridT(VOX / 256);   // conv3x3t: 256 voxels/block (128x2x1)

    // block 1
    conv3x3t<8, true ><<<gridT, blk, 0, stream>>>(x,  ac1_w1, ac1_b1, R0);
    conv8x27n<WT><<<gridN, blk, 0, stream>>>(R0, ac1_w2, WB);
    aconv<8, false, WT><<<grid, blk, 0, stream>>>(x,  WB, R1);
    aconv<8, false, WT><<<grid, blk, 0, stream>>>(R1, WB, R0);
    aconv<8, false, WT><<<grid, blk, 0, stream>>>(R0, WB, R1);
    // mid conv
    conv3x3t<8, false><<<gridT, blk, 0, stream>>>(R1, mid_w, mid_b, R0);
    // block 2
    conv3x3t<8, true ><<<gridT, blk, 0, stream>>>(R0, ac2_w1, ac2_b1, R1);
    conv8x27n<WT><<<gridN, blk, 0, stream>>>(R1, ac2_w2, WB);
    aconv<8, false, WT><<<grid, blk, 0, stream>>>(R0, WB, R1);
    aconv<8, false, WT><<<grid, blk, 0, stream>>>(R1, WB, R0);
    aconv<8, false, WT><<<grid, blk, 0, stream>>>(R0, WB, R1);   // mid2
    // block 3: weights from mid2 (R1)
    conv3x3t<8, true ><<<gridT, blk, 0, stream>>>(R1, ac3_w1, ac3_b1, R0);
    conv8x27n<WT><<<gridN, blk, 0, stream>>>(R0, ac3_w2, WB);
    conv3x3t<1, false><<<gridT, blk, 0, stream>>>(R1, out_w, out_b, F1);
    aconv<1, false, WT><<<grid, blk, 0, stream>>>(F1, WB, F2);
    aconv<1, false, WT><<<grid, blk, 0, stream>>>(F2, WB, F1);
    aconv<1, true,  WT><<<grid, blk, 0, stream>>>(F1, WB, out);
}

extern "C" void kernel_launch(void* const* d_in, const int* in_sizes, int n_in,
                              void* d_out, int out_size, void* d_ws, size_t ws_size,
                              hipStream_t stream)
{
    const float* x = (const float*)d_in[0];
    float* out = (float*)d_out;

    char* ws = (char*)d_ws;
    const size_t CH8 = (size_t)8 * VOX * sizeof(float);          // 64 MB region
    float* R0 = (float*)(ws);
    float* R1 = (float*)(ws + CH8);
    void*  WBp = (void*)(ws + 2 * CH8);

    const size_t need_f32 = 2 * CH8 + (size_t)27 * VOX * sizeof(float);   // 344 MB

    if (ws_size >= need_f32) {
        run_pipeline<float>(x, d_in, out, R0, R1, (float*)WBp, stream);
    } else {
        run_pipeline<_Float16>(x, d_in, out, R0, R1, (_Float16*)WBp, stream);
    }
}